// Round 10
// baseline (440.779 us; speedup 1.0000x reference)
//
#include <hip/hip_runtime.h>
#include <hip/hip_bf16.h>

#define BB 256
#define TT 512
#define EE 300
#define G4 200     // 4*H1
#define NPAD 208   // padded gate dim (13*16)
#define KP 1216    // split K': 4*300 padded to 19*64
#define KC 64      // K' per chunk
#define KPD (KP/2) // 608 dwords per Btg row
#define KCD (KC/2) // 32 dwords per chunk
#define NCH 19
#define NT 13      // N tiles of 16
#define BOFF 8192  // B region byte offset inside a buffer
#define BUFB 34816 // bytes per buffer: A 8192 + B 208*128 = 26624

typedef __attribute__((ext_vector_type(8))) short short8v;
typedef __attribute__((ext_vector_type(4))) float float4v;
typedef __attribute__((ext_vector_type(4))) unsigned int uint4v;

// permuted gate col: col jp corresponds to W row (jp&3)*50 + (jp>>2).

__device__ __forceinline__ float sigm(float x) {
    return __builtin_amdgcn_rcpf(1.f + __builtin_amdgcn_exp2f(-1.442695040888963f * x));
}
__device__ __forceinline__ float tanh_(float x) {
    float t = __builtin_amdgcn_exp2f(2.885390081777927f * x);   // e^(2x)
    return 1.f - 2.f * __builtin_amdgcn_rcpf(t + 1.f);
}
template <int C>
__device__ __forceinline__ float qb(float v) {
    return __int_as_float(__builtin_amdgcn_mov_dpp(__float_as_int(v), C, 0xF, 0xF, true));
}

// split a into bf16 hi/lo (RNE): a ~= hi + lo, err ~2^-16 rel
__device__ __forceinline__ uint2 bfsplit(float a) {
    unsigned u = __float_as_uint(a);
    unsigned rh = (u + 0x7FFFu + ((u >> 16) & 1u)) & 0xFFFF0000u;
    float l = a - __uint_as_float(rh);
    unsigned v = __float_as_uint(l);
    unsigned rl = (v + 0x7FFFu + ((v >> 16) & 1u)) >> 16;
    return make_uint2(rh >> 16, rl);
}

// ---------------------------------------------------------------------------
// K1: build split-bf16 B' [NPAD][KP] (row-major) and permuted bias.
__global__ void wtrans_kernel(const float* __restrict__ W, const float* __restrict__ b1,
                              unsigned* __restrict__ Btg, float* __restrict__ b1p) {
    int e = blockIdx.x;        // 0..299
    int j = threadIdx.x;       // 0..255, valid < 208
    if (j >= NPAD) return;
    float w = 0.f;
    if (j < G4) w = W[((j & 3) * 50 + (j >> 2)) * EE + e];
    uint2 s = bfsplit(w);
    unsigned dw0 = s.x | (s.x << 16);
    unsigned dw1 = s.y | (s.y << 16);
    *(uint2*)(Btg + (size_t)j * KPD + 2 * e) = make_uint2(dw0, dw1);
    if (e == 0) b1p[j] = (j < G4) ? b1[(j & 3) * 50 + (j >> 2)] : 0.f;
}

// ---------------------------------------------------------------------------
// K2: MFMA proj (unchanged from R8's working version).
__global__ __launch_bounds__(256, 2) void proj_kernel(
    const int* __restrict__ x, const int* __restrict__ lengths,
    const float* __restrict__ emb, const unsigned* __restrict__ Btg,
    const float* __restrict__ b1p, float* __restrict__ G1, int b0)
{
    const int b  = b0 + blockIdx.y;
    const int t0 = blockIdx.x * 64;
    const int len = lengths[b];
    if (t0 >= len) return;

    const int tid  = threadIdx.x;
    const int wv   = tid >> 6;
    const int lane = tid & 63;

    __shared__ __align__(16) char lds[2 * BUFB];

    const int arow = tid >> 2;
    const int ag   = tid & 3;
    const float* er = emb + (size_t)x[b * TT + t0 + arow] * EE;

    float4v acc[NT] = {};

    auto stageB = [&](int c, int q) {
        char* base = lds + q * BUFB + BOFF;
        #pragma unroll
        for (int rr = 0; rr < 7; ++rr) {
            if (rr < 6 || tid < 128) {
                int g   = rr * 256 + tid;
                int row = g >> 3, sl = g & 7;
                const unsigned* src = Btg + (size_t)row * KPD + c * KCD
                                      + ((sl ^ (row & 7)) << 2);
                char* dst = base + (rr * 256 + (tid & ~63)) * 16;
                __builtin_amdgcn_global_load_lds(
                    (const __attribute__((address_space(1))) void*)src,
                    (__attribute__((address_space(3))) void*)dst, 16, 0, 0);
            }
        }
    };
    auto loadA = [&](int cc) -> float4 {
        int k0 = cc * 16 + ag * 4;
        if (k0 < EE) return *(const float4*)(er + k0);
        return make_float4(0.f, 0.f, 0.f, 0.f);
    };
    auto writeA = [&](int q, float4 av) {
        uint2 s0 = bfsplit(av.x), s1 = bfsplit(av.y);
        uint2 s2 = bfsplit(av.z), s3 = bfsplit(av.w);
        unsigned p0 = s0.x | (s0.y << 16), p1 = s1.x | (s1.y << 16);
        unsigned p2 = s2.x | (s2.y << 16), p3 = s3.x | (s3.y << 16);
        char* base = lds + q * BUFB + (arow << 7);
        int r7 = arow & 7;
        *(uint4v*)(base + ((( 2 * ag    ) ^ r7) << 4)) = uint4v{p0, p0, p1, p1};
        *(uint4v*)(base + (((2 * ag + 1) ^ r7) << 4)) = uint4v{p2, p2, p3, p3};
    };

    stageB(0, 0);
    float4 aval = loadA(0);
    asm volatile("s_waitcnt vmcnt(0)" ::: "memory");
    writeA(0, aval);
    asm volatile("s_waitcnt lgkmcnt(0)" ::: "memory");
    __builtin_amdgcn_s_barrier();
    __builtin_amdgcn_sched_barrier(0);

    int p = 0;
    for (int c = 0; c < NCH; ++c) {
        const int q = p ^ 1;
        if (c + 1 < NCH) {
            stageB(c + 1, q);
            aval = loadA(c + 1);
        }
        const int r  = lane & 15;
        const int h  = lane >> 4;
        #pragma unroll
        for (int s = 0; s < 2; ++s) {
            const int sw4 = (((4 * s + h) ^ (r & 7)) << 4);
            short8v aF = *(const short8v*)(lds + p * BUFB + ((wv * 16 + r) << 7) + sw4);
            #pragma unroll
            for (int nt = 0; nt < NT; ++nt) {
                short8v bF = *(const short8v*)(lds + p * BUFB + BOFF
                                               + ((nt * 16 + r) << 7) + sw4);
                acc[nt] = __builtin_amdgcn_mfma_f32_16x16x32_bf16(aF, bF, acc[nt], 0, 0, 0);
            }
        }
        if (c + 1 < NCH) {
            asm volatile("s_waitcnt vmcnt(0)" ::: "memory");
            writeA(q, aval);
            asm volatile("s_waitcnt lgkmcnt(0)" ::: "memory");
            __builtin_amdgcn_s_barrier();
            __builtin_amdgcn_sched_barrier(0);
        }
        p = q;
    }

    float* gbase = G1 + ((size_t)blockIdx.y * TT + t0) * G4;
    const int col = lane & 15, rq = lane >> 4;
    #pragma unroll
    for (int nt = 0; nt < NT; ++nt) {
        int jp = nt * 16 + col;
        if (jp < G4) {
            float bias = b1p[jp];
            #pragma unroll
            for (int rr = 0; rr < 4; ++rr)
                gbase[(size_t)(wv * 16 + rq * 4 + rr) * G4 + jp] = acc[nt][rr] + bias;
        }
    }
}

// ---------------------------------------------------------------------------
// K3: recurrence. 256 thr = 4 waves; TWO batch elements per block (2 waves
// each). Lane et=tid&127: unit u=et>>1 (0..59: 0-49 LSTM1, 50-59 LSTM2),
// parity p=et&1 owns gates (2p, 2p+1) as two full 60-dots from registers;
// partner's sums via one quad-perm DPP swap (no LDS). One barrier per step.
// L2 lags one step (mylen=len+1); frozen lanes rewrite old h (mask semantics).
__global__ __launch_bounds__(256, 1) void lstm_kernel(
    const int* __restrict__ lengths,
    const float* __restrict__ W_hh1, const float* __restrict__ W_ih2,
    const float* __restrict__ W_hh2, const float* __restrict__ b2,
    const float* __restrict__ fc1w, const float* __restrict__ fc1b,
    const float* __restrict__ fc2w, const float* __restrict__ fc2b,
    const float* __restrict__ G1, float* __restrict__ out, int b0, int nb)
{
    const int tid = threadIdx.x;
    const int e   = tid >> 7;              // element slot 0/1 (wave-uniform)
    const int et  = tid & 127;
    const int u   = et >> 1;
    const int p   = et & 1;
    const bool act  = et < 120;
    const bool isL1 = act && (u < 50);
    const bool isL2 = act && (u >= 50);

    const int last = b0 + nb - 1;
    int eg = b0 + blockIdx.x * 2 + e;
    if (eg > last) eg = last;
    const int len = lengths[eg];
    const int ego = b0 + blockIdx.x * 2;
    const int eg1 = (ego + 1 > last) ? last : ego + 1;
    const int lenmax = max(lengths[ego], lengths[eg1]);

    __shared__ __align__(16) float hsb[2][2][64];   // [elem][buf][slot]
    __shared__ float hfin[2][12];
    __shared__ float zs[2][12];
    ((float*)hsb)[tid] = 0.f;                       // 256 floats exactly

    // ---- weights: two 60-dots per lane (zero-padded)
    float wA[60], wB[60];
    #pragma unroll
    for (int k = 0; k < 60; ++k) { wA[k] = 0.f; wB[k] = 0.f; }
    float baseA0 = 0.f, baseB0 = 0.f;

    if (isL1) {
        const float* a  = W_hh1 + ((2 * p) * 50 + u) * 50;
        const float* bp = W_hh1 + ((2 * p + 1) * 50 + u) * 50;
        #pragma unroll
        for (int k = 0; k < 50; ++k) { wA[k] = a[k]; wB[k] = bp[k]; }
    } else if (isL2) {
        int u2 = u - 50;
        int rA = (2 * p) * 10 + u2, rB = (2 * p + 1) * 10 + u2;
        #pragma unroll
        for (int k = 0; k < 50; ++k) { wA[k] = W_ih2[rA * 50 + k]; wB[k] = W_ih2[rB * 50 + k]; }
        #pragma unroll
        for (int k = 0; k < 10; ++k) { wA[50 + k] = W_hh2[rA * 10 + k]; wB[50 + k] = W_hh2[rB * 10 + k]; }
        baseA0 = b2[rA]; baseB0 = b2[rB];
    }

    const int mylen = isL2 ? len + 1 : len;
    const int gcol  = isL1 ? (4 * u + 2 * p) : 0;
    const float* g1p = G1 + (size_t)(eg - b0) * TT * G4;

    // 3-deep G1 prefetch (float2 = the lane's two gate columns)
    float2 pf0, pf1, pf2;
    {
        int t1 = (1 < len) ? 1 : len - 1;
        int t2 = (2 < len) ? 2 : len - 1;
        pf0 = *(const float2*)(g1p + gcol);
        pf1 = *(const float2*)(g1p + (size_t)t1 * G4 + gcol);
        pf2 = *(const float2*)(g1p + (size_t)t2 * G4 + gcol);
    }

    float c = 0.f, hown = 0.f;
    __syncthreads();                                // LDS zero-init visible

    int pb = 0;
    for (int i = 0; i < lenmax; ++i) {
        float baseA = isL1 ? pf0.x : baseA0;
        float baseB = isL1 ? pf0.y : baseB0;
        pf0 = pf1; pf1 = pf2;
        {
            int tn = (i + 3 < len) ? i + 3 : len - 1;
            pf2 = *(const float2*)(g1p + (size_t)tn * G4 + gcol);  // in flight
        }

        float sA0 = 0.f, sA1 = 0.f, sA2 = 0.f, sA3 = 0.f;
        float sB0 = 0.f, sB1 = 0.f, sB2 = 0.f, sB3 = 0.f;
        const float* hb = &hsb[e][pb][0];
        #pragma unroll
        for (int m = 0; m < 15; ++m) {
            float4 hv = *(const float4*)(hb + 4 * m);
            sA0 = fmaf(wA[4*m+0], hv.x, sA0);
            sA1 = fmaf(wA[4*m+1], hv.y, sA1);
            sA2 = fmaf(wA[4*m+2], hv.z, sA2);
            sA3 = fmaf(wA[4*m+3], hv.w, sA3);
            sB0 = fmaf(wB[4*m+0], hv.x, sB0);
            sB1 = fmaf(wB[4*m+1], hv.y, sB1);
            sB2 = fmaf(wB[4*m+2], hv.z, sB2);
            sB3 = fmaf(wB[4*m+3], hv.w, sB3);
        }
        float tA = baseA + (sA0 + sA1) + (sA2 + sA3);
        float tB = baseB + (sB0 + sB1) + (sB2 + sB3);
        float qA = qb<0xB1>(tA);                    // partner's two sums
        float qB = qb<0xB1>(tB);
        float gi = p ? qA : tA;
        float gf = p ? qB : tB;
        float gg = p ? tA : qA;
        float go = p ? tB : qB;
        float cn = sigm(gf) * c + sigm(gi) * tanh_(gg);
        float hn = sigm(go) * tanh_(cn);
        if (isL2 && i == 0) { cn = 0.f; hn = 0.f; } // h2(-1)=0
        bool upd = (i < mylen);
        if (upd) c = cn;
        float hw = upd ? hn : hown;                 // freeze rewrites old value
        hown = hw;
        if (act && p == 0) hsb[e][pb ^ 1][u] = hw;

        asm volatile("s_waitcnt lgkmcnt(0)" ::: "memory");
        __builtin_amdgcn_s_barrier();
        __builtin_amdgcn_sched_barrier(0);
        pb ^= 1;
    }

    // ---- tail: for len==lenmax elements, L2 needs one more eval
    {
        float sA0 = 0.f, sA1 = 0.f, sA2 = 0.f, sA3 = 0.f;
        float sB0 = 0.f, sB1 = 0.f, sB2 = 0.f, sB3 = 0.f;
        const float* hb = &hsb[e][pb][0];
        #pragma unroll
        for (int m = 0; m < 15; ++m) {
            float4 hv = *(const float4*)(hb + 4 * m);
            sA0 = fmaf(wA[4*m+0], hv.x, sA0);
            sA1 = fmaf(wA[4*m+1], hv.y, sA1);
            sA2 = fmaf(wA[4*m+2], hv.z, sA2);
            sA3 = fmaf(wA[4*m+3], hv.w, sA3);
            sB0 = fmaf(wB[4*m+0], hv.x, sB0);
            sB1 = fmaf(wB[4*m+1], hv.y, sB1);
            sB2 = fmaf(wB[4*m+2], hv.z, sB2);
            sB3 = fmaf(wB[4*m+3], hv.w, sB3);
        }
        float tA = baseA0 + (sA0 + sA1) + (sA2 + sA3);
        float tB = baseB0 + (sB0 + sB1) + (sB2 + sB3);
        float qA = qb<0xB1>(tA);
        float qB = qb<0xB1>(tB);
        float gi = p ? qA : tA;
        float gf = p ? qB : tB;
        float gg = p ? tA : qA;
        float go = p ? tB : qB;
        float cn = sigm(gf) * c + sigm(gi) * tanh_(gg);
        float hn = sigm(go) * tanh_(cn);
        float h2f = (len == lenmax) ? hn : hown;
        if (isL2 && p == 0) hfin[e][u - 50] = h2f;
    }
    __syncthreads();

    // ---- MLP head (per element)
    if (et < 10) {
        float s = fc1b[et];
        #pragma unroll
        for (int k = 0; k < 10; ++k) s = fmaf(fc1w[et * 10 + k], hfin[e][k], s);
        zs[e][et] = s > 0.f ? s : 0.f;
    }
    __syncthreads();
    if (et == 0) {
        float s = fc2b[0];
        #pragma unroll
        for (int k = 0; k < 10; ++k) s = fmaf(fc2w[k], zs[e][k], s);
        out[eg] = s;
    }
}

// ---------------------------------------------------------------------------
extern "C" void kernel_launch(void* const* d_in, const int* in_sizes, int n_in,
                              void* d_out, int out_size, void* d_ws, size_t ws_size,
                              hipStream_t stream)
{
    const int*   x     = (const int*)  d_in[0];
    const int*   len   = (const int*)  d_in[1];
    const float* emb   = (const float*)d_in[2];
    const float* W_ih1 = (const float*)d_in[3];
    const float* W_hh1 = (const float*)d_in[4];
    const float* b1    = (const float*)d_in[5];
    const float* W_ih2 = (const float*)d_in[6];
    const float* W_hh2 = (const float*)d_in[7];
    const float* b2    = (const float*)d_in[8];
    const float* fc1w  = (const float*)d_in[9];
    const float* fc1b  = (const float*)d_in[10];
    const float* fc2w  = (const float*)d_in[11];
    const float* fc2b  = (const float*)d_in[12];
    float* out = (float*)d_out;

    const size_t btg_bytes = (size_t)NPAD * KPD * sizeof(unsigned);  // 505856
    const size_t b1p_off   = btg_bytes;
    const size_t head      = (b1p_off + NPAD * sizeof(float) + 255) & ~255ull;
    const size_t per_b     = (size_t)TT * G4 * sizeof(float);        // 409600

    unsigned* Btg = (unsigned*)d_ws;
    float*    b1p = (float*)((char*)d_ws + b1p_off);
    float*    G1  = (float*)((char*)d_ws + head);

    size_t avail = ws_size > head ? ws_size - head : 0;
    int chunk = (int)(avail / per_b);
    if (chunk < 1) chunk = 1;
    if (chunk > BB) chunk = BB;

    wtrans_kernel<<<dim3(EE), dim3(256), 0, stream>>>(W_ih1, b1, Btg, b1p);

    for (int b0 = 0; b0 < BB; b0 += chunk) {
        int nb = (BB - b0) < chunk ? (BB - b0) : chunk;
        proj_kernel<<<dim3(TT / 64, nb), dim3(256), 0, stream>>>(
            x, len, emb, Btg, b1p, G1, b0);
        lstm_kernel<<<dim3((nb + 1) / 2), dim3(256), 0, stream>>>(
            len, W_hh1, W_ih2, W_hh2, b2, fc1w, fc1b, fc2w, fc2b, G1, out, b0, nb);
    }
}